// Round 13
// baseline (220.880 us; speedup 1.0000x reference)
//
#include <hip/hip_runtime.h>
#include <hip/hip_bf16.h>

// FConv2d, round 18 = round-17 structure + DIAGNOSTIC rep-loop (reps=5).
// r17 (XCD swizzle + full-line stores) gave only 10% (fconv 26->23.6us) vs
// predicted 50% -> falsifier fired. This round measures FETCH/WRITE per rep
// ON THE SWIZZLED STRUCTURE to disambiguate:
//   FETCH/rep ~47MB unchanged  -> swizzle never achieved locality
//   FETCH/rep ~15-25MB         -> locality OK, bottleneck moved (read
//                                 MfmaUtil/VALUBusy/Occ for the new pipe)
//   WRITE/rep >> 17MB          -> dirty-eviction churn independent of x
// Body idempotent; reps runtime arg; end-of-rep barrier protects restage.
// Structure IDENTICAL to r17 (verified, absmax 0.015625):
//  - 1-D grid 512, b=(bid&7)+8*((bid>>3)&1), r=bid>>4 (batch->XCD swizzle)
//  - one output row/block, stage 3 rows; waves = 8 d-groups
//    {0,8},{4},{2},{6},{1},{5},{3},{7}, each loops both col-halves
//    (full 128-B line stores from one wave).

typedef __attribute__((ext_vector_type(8))) short short8;
typedef __attribute__((ext_vector_type(4))) float floatx4;

#define NT 512
#define LCH 168                 // padded channel-slot dim (160 used)
#define SROWS 34                // cols per staged row (32..33 zero apron)
#define XSROW (SROWS * LCH)

template<int D, bool DUP>
__device__ __forceinline__ void compute_d(const char* basep, const short8 af[9],
                                          float* opbase) {
    floatx4 a0 = {0.f,0.f,0.f,0.f}, a1 = {0.f,0.f,0.f,0.f};
    floatx4 b0 = {0.f,0.f,0.f,0.f}, b1 = {0.f,0.f,0.f,0.f};
#pragma unroll
    for (int u = 0; u < 3; ++u)
#pragma unroll
        for (int v = 0; v < 3; ++v) {
            const int t = u * 3 + v;
            const short8 ba = *(const short8*)(basep +
                ((u * SROWS + v) * LCH + 8 * (8 + D)) * 2);
            if (t & 1) a1 = __builtin_amdgcn_mfma_f32_16x16x32_bf16(af[t], ba, a1, 0, 0, 0);
            else       a0 = __builtin_amdgcn_mfma_f32_16x16x32_bf16(af[t], ba, a0, 0, 0, 0);
            if (!DUP) {
                const short8 bb = *(const short8*)(basep +
                    ((u * SROWS + v) * LCH + 8 * (8 - D)) * 2);
                if (t & 1) b1 = __builtin_amdgcn_mfma_f32_16x16x32_bf16(af[t], bb, b1, 0, 0, 0);
                else       b0 = __builtin_amdgcn_mfma_f32_16x16x32_bf16(af[t], bb, b0, 0, 0, 0);
            }
        }
    floatx4 acc = a0 + a1;
    if (DUP) acc = acc + acc;          // xa==xb: 2*(0.5W*xa) = W*xa, bit-identical
    else     acc = acc + (b0 + b1);
    float* op = opbase + D * 16384;    // D*16*1024 floats
    op[0]    = acc.x;
    op[1024] = acc.y;
    op[2048] = acc.z;
    op[3072] = acc.w;
    if (D >= 1 && D <= 7) {            // mirror channel group 16-D
        float* op2 = opbase + (16 - D) * 16384;
        op2[0]    = acc.x;
        op2[1024] = acc.y;
        op2[2048] = acc.z;
        op2[3072] = acc.w;
    }
}

__global__ __launch_bounds__(NT, 4)
void fconv_mfma(const float* __restrict__ x,
                const float* __restrict__ wgt,
                float* __restrict__ out,
                int reps) {
    __shared__ __align__(16) short xs[3 * XSROW];   // 34,272 B
    __shared__ __align__(16) short wf[9 * 640];     // 11,520 B

    const int bid = blockIdx.x;    // 0..511
    const int b   = (bid & 7) + (((bid >> 3) & 1) << 3);   // batch->XCD swizzle
    const int r   = bid >> 4;                              // 0..31
    const int tid  = threadIdx.x;
    const int lane = tid & 63;
    const int wv   = tid >> 6;

    for (int rep = 0; rep < reps; ++rep) {

    // ---- weights -> LDS: wf[(8-k)*640 + n*40 + oct*8 + (7-j)] = 0.5*W[n][8oct+j][k]
    {
        const int nn = tid >> 5;        // 0..15
        const int c2 = tid & 31;
        const float* wb = wgt + (size_t)(nn * 32 + c2) * 9;
        const int pos = nn * 40 + (c2 & 24) + (7 - (c2 & 7));
#pragma unroll
        for (int k = 0; k < 9; ++k) {
            __hip_bfloat16 h = __float2bfloat16(0.5f * wb[k]);
            wf[(8 - k) * 640 + pos] = __builtin_bit_cast(short, h);
        }
    }

    // ---- stage raw x rows r..r+2: 1920 granule tasks (lrow, col, oL) ----
    const float* xb_base = x + ((size_t)b << 17);
#pragma unroll
    for (int it = 0; it < 4; ++it) {
        const int idx = it * NT + tid;            // 0..2047
        if (idx < 1920) {
            const int col  = idx & 31;
            const int rest = idx >> 5;            // 0..59
            const int oL   = rest / 3;            // 0..19
            const int lrow = rest - oL * 3;       // 0..2
            const int grow = r + lrow;
            short8 g;
            if (grow < 32) {
                float v[8];
#pragma unroll
                for (int j = 0; j < 8; ++j) {
                    const int m = (oL * 8 + j - 95) & 127;   // channel (L-95) mod 128
                    v[j] = xb_base[((m << 5) + grow) * 32 + col];
                }
                union { __hip_bfloat162 h2[4]; short8 s8; } u;
#pragma unroll
                for (int p = 0; p < 4; ++p)
                    u.h2[p] = __float22bfloat162_rn(make_float2(v[2 * p], v[2 * p + 1]));
                g = u.s8;
            } else {
                g = short8{0, 0, 0, 0, 0, 0, 0, 0};
            }
            *(short8*)&xs[(lrow * SROWS + col) * LCH + oL * 8] = g;
        }
    }
    // s-apron (col 32,33) zeros: 3 lrow * 2 col * 20 oL = 120 granules
    if (tid < 120) {
        const int oL   = tid % 20;
        const int rem  = tid / 20;       // 0..5
        const int lrow = rem >> 1;
        const int col  = 32 + (rem & 1);
        short8 z = {0, 0, 0, 0, 0, 0, 0, 0};
        *(short8*)&xs[(lrow * SROWS + col) * LCH + oL * 8] = z;
    }

    __syncthreads();

    // ---- A fragments: 9 ds_read_b128 ----
    const int n = lane & 15;      // filter row / D col lane
    const int q = lane >> 4;      // k-octet
    short8 af[9];
#pragma unroll
    for (int t = 0; t < 9; ++t)
        af[t] = *(const short8*)&wf[t * 640 + n * 40 + q * 8];

    // ---- compute: wave = one d-group, BOTH col-halves (full-line stores) ----
#pragma unroll
    for (int i = 0; i < 2; ++i) {
        const int s0 = i << 4;
        const char* basep = (const char*)xs + ((s0 + n) * LCH + 8 * (3 - q)) * 2;
        float* opbase = out + ((size_t)((b * 256 + q * 4) * 32 + r) << 5) + s0 + n;
        switch (wv) {
        case 0: compute_d<0, true >(basep, af, opbase);
                compute_d<8, true >(basep, af, opbase); break;  // 18 MFMA
        case 1: compute_d<4, false>(basep, af, opbase); break;  // 18
        case 2: compute_d<2, false>(basep, af, opbase); break;
        case 3: compute_d<6, false>(basep, af, opbase); break;
        case 4: compute_d<1, false>(basep, af, opbase); break;
        case 5: compute_d<5, false>(basep, af, opbase); break;
        case 6: compute_d<3, false>(basep, af, opbase); break;
        default: compute_d<7, false>(basep, af, opbase); break;
        }
    }

    __syncthreads();   // protect LDS restage of next rep
    }                  // rep loop
}

extern "C" void kernel_launch(void* const* d_in, const int* in_sizes, int n_in,
                              void* d_out, int out_size, void* d_ws, size_t ws_size,
                              hipStream_t stream) {
    const float* x   = (const float*)d_in[0];   // (16,128,32,32) fp32
    const float* wgt = (const float*)d_in[1];   // (16,32,3,3)   fp32
    float* out = (float*)d_out;                 // (16,256,32,32) fp32
    (void)in_sizes; (void)n_in; (void)out_size; (void)d_ws; (void)ws_size;

    fconv_mfma<<<dim3(512), dim3(NT), 0, stream>>>(x, wgt, out, 5);
}

// Round 14
// 68.169 us; speedup vs baseline: 3.2402x; 3.2402x over previous
//
#include <hip/hip_runtime.h>
#include <hip/hip_bf16.h>

// FConv2d, round 19: r17 structure + NONTEMPORAL out stores.
// r18 diagnostic: FETCH 47->34 MB/rep (swizzle works) but WRITE 45->77
// MB/rep (4.6x out size). Write path dominates: (a) out RFO fetches
// (~16.8MB), (b) poison-dirty L2 eviction writebacks, (c) half-dirty
// line eviction churn (i-loop separates the two 64-B halves in time).
// Fix: __builtin_nontemporal_store for ALL out stores -> no RFO, no L2
// dirty accumulation; HBM granule is 64B so 64-B segments stream clean.
// Everything else IDENTICAL to r17 (verified, absmax 0.015625):
//  - 1-D grid 512, b=(bid&7)+8*((bid>>3)&1), r=bid>>4 (batch->XCD swizzle)
//  - one output row/block, stage 3 rows; waves = 8 d-groups
//    {0,8},{4},{2},{6},{1},{5},{3},{7}, each loops both col-halves.
// Identity: out[b,d*16+n,r,s] = sum 0.5W[n,c2,2-u,2-v]*(xa+xb)[r+u,s+v];
// d=0/8: xa==xb -> acc doubled; mirror d'=16-d same acc.

typedef __attribute__((ext_vector_type(8))) short short8;
typedef __attribute__((ext_vector_type(4))) float floatx4;

#define NT 512
#define LCH 168                 // padded channel-slot dim (160 used)
#define SROWS 34                // cols per staged row (32..33 zero apron)
#define XSROW (SROWS * LCH)

template<int D, bool DUP>
__device__ __forceinline__ void compute_d(const char* basep, const short8 af[9],
                                          float* opbase) {
    floatx4 a0 = {0.f,0.f,0.f,0.f}, a1 = {0.f,0.f,0.f,0.f};
    floatx4 b0 = {0.f,0.f,0.f,0.f}, b1 = {0.f,0.f,0.f,0.f};
#pragma unroll
    for (int u = 0; u < 3; ++u)
#pragma unroll
        for (int v = 0; v < 3; ++v) {
            const int t = u * 3 + v;
            const short8 ba = *(const short8*)(basep +
                ((u * SROWS + v) * LCH + 8 * (8 + D)) * 2);
            if (t & 1) a1 = __builtin_amdgcn_mfma_f32_16x16x32_bf16(af[t], ba, a1, 0, 0, 0);
            else       a0 = __builtin_amdgcn_mfma_f32_16x16x32_bf16(af[t], ba, a0, 0, 0, 0);
            if (!DUP) {
                const short8 bb = *(const short8*)(basep +
                    ((u * SROWS + v) * LCH + 8 * (8 - D)) * 2);
                if (t & 1) b1 = __builtin_amdgcn_mfma_f32_16x16x32_bf16(af[t], bb, b1, 0, 0, 0);
                else       b0 = __builtin_amdgcn_mfma_f32_16x16x32_bf16(af[t], bb, b0, 0, 0, 0);
            }
        }
    floatx4 acc = a0 + a1;
    if (DUP) acc = acc + acc;          // xa==xb: 2*(0.5W*xa) = W*xa, bit-identical
    else     acc = acc + (b0 + b1);
    float* op = opbase + D * 16384;    // D*16*1024 floats
    __builtin_nontemporal_store(acc.x, op);
    __builtin_nontemporal_store(acc.y, op + 1024);
    __builtin_nontemporal_store(acc.z, op + 2048);
    __builtin_nontemporal_store(acc.w, op + 3072);
    if (D >= 1 && D <= 7) {            // mirror channel group 16-D
        float* op2 = opbase + (16 - D) * 16384;
        __builtin_nontemporal_store(acc.x, op2);
        __builtin_nontemporal_store(acc.y, op2 + 1024);
        __builtin_nontemporal_store(acc.z, op2 + 2048);
        __builtin_nontemporal_store(acc.w, op2 + 3072);
    }
}

__global__ __launch_bounds__(NT, 4)
void fconv_mfma(const float* __restrict__ x,
                const float* __restrict__ wgt,
                float* __restrict__ out) {
    __shared__ __align__(16) short xs[3 * XSROW];   // 34,272 B
    __shared__ __align__(16) short wf[9 * 640];     // 11,520 B

    const int bid = blockIdx.x;    // 0..511
    const int b   = (bid & 7) + (((bid >> 3) & 1) << 3);   // batch->XCD swizzle
    const int r   = bid >> 4;                              // 0..31
    const int tid  = threadIdx.x;
    const int lane = tid & 63;
    const int wv   = tid >> 6;

    // ---- weights -> LDS: wf[(8-k)*640 + n*40 + oct*8 + (7-j)] = 0.5*W[n][8oct+j][k]
    {
        const int nn = tid >> 5;        // 0..15
        const int c2 = tid & 31;
        const float* wb = wgt + (size_t)(nn * 32 + c2) * 9;
        const int pos = nn * 40 + (c2 & 24) + (7 - (c2 & 7));
#pragma unroll
        for (int k = 0; k < 9; ++k) {
            __hip_bfloat16 h = __float2bfloat16(0.5f * wb[k]);
            wf[(8 - k) * 640 + pos] = __builtin_bit_cast(short, h);
        }
    }

    // ---- stage raw x rows r..r+2: 1920 granule tasks (lrow, col, oL) ----
    const float* xb_base = x + ((size_t)b << 17);
#pragma unroll
    for (int it = 0; it < 4; ++it) {
        const int idx = it * NT + tid;            // 0..2047
        if (idx < 1920) {
            const int col  = idx & 31;
            const int rest = idx >> 5;            // 0..59
            const int oL   = rest / 3;            // 0..19
            const int lrow = rest - oL * 3;       // 0..2
            const int grow = r + lrow;
            short8 g;
            if (grow < 32) {
                float v[8];
#pragma unroll
                for (int j = 0; j < 8; ++j) {
                    const int m = (oL * 8 + j - 95) & 127;   // channel (L-95) mod 128
                    v[j] = xb_base[((m << 5) + grow) * 32 + col];
                }
                union { __hip_bfloat162 h2[4]; short8 s8; } u;
#pragma unroll
                for (int p = 0; p < 4; ++p)
                    u.h2[p] = __float22bfloat162_rn(make_float2(v[2 * p], v[2 * p + 1]));
                g = u.s8;
            } else {
                g = short8{0, 0, 0, 0, 0, 0, 0, 0};
            }
            *(short8*)&xs[(lrow * SROWS + col) * LCH + oL * 8] = g;
        }
    }
    // s-apron (col 32,33) zeros: 3 lrow * 2 col * 20 oL = 120 granules
    if (tid < 120) {
        const int oL   = tid % 20;
        const int rem  = tid / 20;       // 0..5
        const int lrow = rem >> 1;
        const int col  = 32 + (rem & 1);
        short8 z = {0, 0, 0, 0, 0, 0, 0, 0};
        *(short8*)&xs[(lrow * SROWS + col) * LCH + oL * 8] = z;
    }

    __syncthreads();

    // ---- A fragments: 9 ds_read_b128 ----
    const int n = lane & 15;      // filter row / D col lane
    const int q = lane >> 4;      // k-octet
    short8 af[9];
#pragma unroll
    for (int t = 0; t < 9; ++t)
        af[t] = *(const short8*)&wf[t * 640 + n * 40 + q * 8];

    // ---- compute: wave = one d-group, BOTH col-halves ----
#pragma unroll
    for (int i = 0; i < 2; ++i) {
        const int s0 = i << 4;
        const char* basep = (const char*)xs + ((s0 + n) * LCH + 8 * (3 - q)) * 2;
        float* opbase = out + ((size_t)((b * 256 + q * 4) * 32 + r) << 5) + s0 + n;
        switch (wv) {
        case 0: compute_d<0, true >(basep, af, opbase);
                compute_d<8, true >(basep, af, opbase); break;  // 18 MFMA
        case 1: compute_d<4, false>(basep, af, opbase); break;  // 18
        case 2: compute_d<2, false>(basep, af, opbase); break;
        case 3: compute_d<6, false>(basep, af, opbase); break;
        case 4: compute_d<1, false>(basep, af, opbase); break;
        case 5: compute_d<5, false>(basep, af, opbase); break;
        case 6: compute_d<3, false>(basep, af, opbase); break;
        default: compute_d<7, false>(basep, af, opbase); break;
        }
    }
}

extern "C" void kernel_launch(void* const* d_in, const int* in_sizes, int n_in,
                              void* d_out, int out_size, void* d_ws, size_t ws_size,
                              hipStream_t stream) {
    const float* x   = (const float*)d_in[0];   // (16,128,32,32) fp32
    const float* wgt = (const float*)d_in[1];   // (16,32,3,3)   fp32
    float* out = (float*)d_out;                 // (16,256,32,32) fp32
    (void)in_sizes; (void)n_in; (void)out_size; (void)d_ws; (void)ws_size;

    fconv_mfma<<<dim3(512), dim3(NT), 0, stream>>>(x, wgt, out);
}